// Round 5
// baseline (11684.245 us; speedup 1.0000x reference)
//
#include <hip/hip_runtime.h>
#include <stdint.h>

// Problem constants (match reference)
#define T_STEPS 1024
#define BATCH   64
#define NDIM    512
#define BN      (BATCH * NDIM)   // 32768
#define ALPHA   0.1f

// ---------------------------------------------------------------------------
// Helpers: bf16 pack/unpack (RNE). Only W is stored bf16; r and accumulation
// stay fp32 -> per-step matmul error ~1e-4*alpha-scaled, contractive
// recurrence (gain ~0.97/step) keeps steady-state error ~3e-3 << 3.1e-2.
// ---------------------------------------------------------------------------
__device__ __forceinline__ unsigned short f2bf(float f) {
    unsigned int u = __float_as_uint(f);
    unsigned int r = (u + 0x7fffu + ((u >> 16) & 1u)) >> 16;  // round-nearest-even
    return (unsigned short)r;
}
__device__ __forceinline__ float bflo(unsigned int d) { return __uint_as_float(d << 16); }
__device__ __forceinline__ float bfhi(unsigned int d) { return __uint_as_float(d & 0xffff0000u); }

// ---------------------------------------------------------------------------
// Prep: build masked, transposed, bf16-packed weights in workspace.
// Layout: Wp[k8 * 512 + n] is a uint4 (16B) holding W_eff[n][8*k8 .. 8*k8+7]
// as 8 bf16 (pairs packed lo=even k, hi=odd k). Consecutive threads (n) hit
// consecutive uint4 -> fully coalesced stores and (in the scan) loads.
// ---------------------------------------------------------------------------
__global__ void rnn_prep_kernel(const float* __restrict__ W_rec,
                                const int* __restrict__ rec_mask,
                                uint4* __restrict__ Wp) {
    const int k8 = blockIdx.x;    // 0..63
    const int n  = threadIdx.x;   // 0..511
    const int base = n * NDIM + k8 * 8;
    unsigned int words[4];
#pragma unroll
    for (int p = 0; p < 4; ++p) {
        float w0 = W_rec[base + 2 * p];
        float w1 = W_rec[base + 2 * p + 1];
        int   m0 = rec_mask[base + 2 * p];
        int   m1 = rec_mask[base + 2 * p + 1];
        unsigned int lo = m0 ? (unsigned int)f2bf(w0) : 0u;
        unsigned int hi = m1 ? (unsigned int)f2bf(w1) : 0u;
        words[p] = lo | (hi << 16);
    }
    uint4 o;
    o.x = words[0]; o.y = words[1]; o.z = words[2]; o.w = words[3];
    Wp[(k8 << 9) | n] = o;
}

// ---------------------------------------------------------------------------
// Scan: one workgroup per batch row (the recurrences are independent across
// batch -> zero inter-WG communication). Thread n owns state column x[n].
// Per step: tanh -> LDS (double-buffered, 1 barrier/step), then
// y[n] = sum_k r[k] * W_eff[n][k] with W streamed from L2 (bf16 x8 per
// dwordx4) and r broadcast from LDS via uniform-address b128 reads.
// 8 independent accumulators break the serial FMA dependency chain.
// ---------------------------------------------------------------------------
__global__ __launch_bounds__(512, 1)
void rnn_scan_kernel(const float* __restrict__ inputs,
                     const float* __restrict__ bias,
                     const float* __restrict__ init_x,
                     const uint4* __restrict__ Wp,
                     float* __restrict__ out) {
    const int b = blockIdx.x;     // 0..63
    const int n = threadIdx.x;    // 0..511

    __shared__ float rs[2][NDIM];

    const float bias_n = bias[n];
    float x = init_x[n];

    // t = 0 output block: broadcast initial state
    out[(size_t)b * NDIM + n] = x;

    const float* u_ptr = inputs + (size_t)b * NDIM + n;
    float*       o_ptr = out + (size_t)BN + (size_t)b * NDIM + n;

    for (int t = 0; t < T_STEPS; ++t) {
        const int buf = t & 1;
        rs[buf][n] = tanhf(x);
        __syncthreads();
        const float* rr = rs[buf];

        float a0 = 0.f, a1 = 0.f, a2 = 0.f, a3 = 0.f;
        float a4 = 0.f, a5 = 0.f, a6 = 0.f, a7 = 0.f;
#pragma unroll 8
        for (int k8 = 0; k8 < 64; ++k8) {
            const uint4 w = Wp[(k8 << 9) | n];
            const float4 ra = *reinterpret_cast<const float4*>(&rr[k8 * 8]);
            const float4 rb = *reinterpret_cast<const float4*>(&rr[k8 * 8 + 4]);
            a0 = fmaf(bflo(w.x), ra.x, a0);
            a1 = fmaf(bfhi(w.x), ra.y, a1);
            a2 = fmaf(bflo(w.y), ra.z, a2);
            a3 = fmaf(bfhi(w.y), ra.w, a3);
            a4 = fmaf(bflo(w.z), rb.x, a4);
            a5 = fmaf(bfhi(w.z), rb.y, a5);
            a6 = fmaf(bflo(w.w), rb.z, a6);
            a7 = fmaf(bfhi(w.w), rb.w, a7);
        }
        const float acc = ((a0 + a1) + (a2 + a3)) + ((a4 + a5) + (a6 + a7));

        const float u = *u_ptr;
        // x_new = x + alpha * (-x + acc + u + bias)
        x = fmaf(ALPHA, (acc + u + bias_n) - x, x);
        *o_ptr = x;

        u_ptr += BN;
        o_ptr += BN;
        // No second barrier needed: next iteration writes the other LDS
        // buffer; a thread can only reach the write of buffer B at t+2
        // after passing the barrier at t+1, which all threads reach only
        // after finishing their t-compute reads of buffer B.
    }
}

// ---------------------------------------------------------------------------
// Launch
// ---------------------------------------------------------------------------
extern "C" void kernel_launch(void* const* d_in, const int* in_sizes, int n_in,
                              void* d_out, int out_size, void* d_ws, size_t ws_size,
                              hipStream_t stream) {
    const float* inputs   = (const float*)d_in[0];  // [T, B, N] fp32
    const float* W_rec    = (const float*)d_in[1];  // [N, N] fp32
    const int*   rec_mask = (const int*)d_in[2];    // [N, N] int (bool)
    const float* bias     = (const float*)d_in[3];  // [1, N] fp32
    const float* init_x   = (const float*)d_in[4];  // [N] fp32
    float*       out      = (float*)d_out;          // [T+1, B, N] fp32

    uint4* Wp = (uint4*)d_ws;  // 512 KB: masked W^T, bf16-packed

    rnn_prep_kernel<<<64, 512, 0, stream>>>(W_rec, rec_mask, Wp);
    rnn_scan_kernel<<<64, 512, 0, stream>>>(inputs, bias, init_x, Wp, out);
}